// Round 2
// baseline (351.450 us; speedup 1.0000x reference)
//
#include <hip/hip_runtime.h>
#include <stdint.h>

#define A_N 9
#define H_N 50
#define W_N 76
#define HW_N (H_N * W_N)      // 3800
#define N_PROP (A_N * HW_N)   // 34200
#define B_N 4
#define PRE_NMS 4000
#define POST_NMS 300
#define NMS_TH 0.7f
#define SORT_N 4096
#define MASK_WORDS 64
#define CAND_MAX 5120
#define NBINS 4096

// ---------------------------------------------------------------------------
// Kernel A: decode boxes + build 64-bit sort keys + 12-bit-bucket histogram
// key = (sortable(score) << 32) | ~index  -> descending order == top_k with
// stable lower-index-first tie-break (matches jax.lax.top_k).
// ---------------------------------------------------------------------------
__global__ void decode_kernel(const float* __restrict__ scores,
                              const float* __restrict__ deltas,
                              const float* __restrict__ im_info,
                              const float* __restrict__ anchors,
                              float4* __restrict__ boxes,
                              unsigned long long* __restrict__ keys,
                              unsigned* __restrict__ ghist) {
#pragma clang fp contract(off)
    int gid = blockIdx.x * blockDim.x + threadIdx.x;
    if (gid >= B_N * N_PROP) return;
    int b = gid / N_PROP;
    int n = gid - b * N_PROP;
    int a = n % A_N;
    int hw = n / A_N;
    int hy = hw / W_N;
    int wx = hw - hy * W_N;

    float sx = (float)wx * 16.0f;
    float sy = (float)hy * 16.0f;
    float ax1 = anchors[a * 4 + 0] + sx;
    float ay1 = anchors[a * 4 + 1] + sy;
    float ax2 = anchors[a * 4 + 2] + sx;
    float ay2 = anchors[a * 4 + 3] + sy;
    float aw = ax2 - ax1 + 1.0f;
    float ah = ay2 - ay1 + 1.0f;
    float cx = ax1 + 0.5f * aw;
    float cy = ay1 + 0.5f * ah;

    const float* db = deltas + ((size_t)b * 36 + (size_t)a * 4) * HW_N + hw;
    float d0 = db[0];
    float d1 = db[HW_N];
    float d2 = db[2 * HW_N];
    float d3 = db[3 * HW_N];

    float pcx = d0 * aw + cx;
    float pcy = d1 * ah + cy;
    float pw  = expf(d2) * aw;
    float ph  = expf(d3) * ah;

    float x1 = pcx - 0.5f * pw;
    float y1 = pcy - 0.5f * ph;
    float x2 = pcx + 0.5f * pw;
    float y2 = pcy + 0.5f * ph;

    float xhi = im_info[b * 3 + 1] - 1.0f;
    float yhi = im_info[b * 3 + 0] - 1.0f;
    x1 = fminf(fmaxf(x1, 0.0f), xhi);
    y1 = fminf(fmaxf(y1, 0.0f), yhi);
    x2 = fminf(fmaxf(x2, 0.0f), xhi);
    y2 = fminf(fmaxf(y2, 0.0f), yhi);

    boxes[gid] = make_float4(x1, y1, x2, y2);

    float s = scores[((size_t)b * A_N + a) * HW_N + hw];
    unsigned f = __float_as_uint(s);
    unsigned sk = f ^ ((f & 0x80000000u) ? 0xFFFFFFFFu : 0x80000000u);
    unsigned long long key = ((unsigned long long)sk << 32) | (unsigned)(~(unsigned)n);
    keys[gid] = key;
    atomicAdd(&ghist[b * NBINS + (unsigned)(key >> 52)], 1u);
}

// ---------------------------------------------------------------------------
// Kernel B: per-image threshold bucket T: smallest bucket such that
// count(bucket >= T) >= PRE_NMS. Grid = B, 64 threads.
// ---------------------------------------------------------------------------
__global__ void findT_kernel(const unsigned* __restrict__ ghist,
                             int* __restrict__ Tout) {
    __shared__ unsigned h[NBINS];
    __shared__ unsigned g[64];
    int b = blockIdx.x;
    int tid = threadIdx.x;  // 64 threads
    for (int i = tid; i < NBINS; i += 64) h[i] = ghist[b * NBINS + i];
    __syncthreads();
    unsigned s = 0;
    for (int j = 0; j < 64; ++j) s += h[tid * 64 + j];
    g[tid] = s;
    __syncthreads();
    if (tid == 0) {
        unsigned run = 0;
        int T = 0;
        for (int gi = 63; gi >= 0; --gi) {
            if (run + g[gi] >= PRE_NMS) {
                for (int j = 63; j >= 0; --j) {
                    run += h[gi * 64 + j];
                    if (run >= PRE_NMS) { T = gi * 64 + j; break; }
                }
                break;
            }
            run += g[gi];
        }
        Tout[b] = T;
    }
}

// ---------------------------------------------------------------------------
// Kernel C: compact candidates (bucket >= T), unordered.
// ---------------------------------------------------------------------------
__global__ void compact_kernel(const unsigned long long* __restrict__ keys,
                               const int* __restrict__ T,
                               unsigned* __restrict__ cnt,
                               unsigned long long* __restrict__ cand) {
    int b = blockIdx.y;
    int n = blockIdx.x * 256 + threadIdx.x;
    if (n >= N_PROP) return;
    unsigned long long k = keys[(size_t)b * N_PROP + n];
    if ((int)(unsigned)(k >> 52) >= T[b]) {
        unsigned p = atomicAdd(&cnt[b], 1u);
        if (p < CAND_MAX) cand[(size_t)b * CAND_MAX + p] = k;
    }
}

// ---------------------------------------------------------------------------
// Kernel D: exact rank by pairwise count (keys unique -> permutation);
// scatter box straight to its sorted position. Pads [4000,4096) with zeros.
// ---------------------------------------------------------------------------
__global__ __launch_bounds__(256) void rank_scatter_kernel(
    const unsigned long long* __restrict__ cand,
    const unsigned* __restrict__ cnt,
    const float4* __restrict__ boxes,
    float4* __restrict__ sortedBoxes) {
    __shared__ unsigned long long sk[256];
    int b = blockIdx.y;
    int tid = threadIdx.x;
    int i = blockIdx.x * 256 + tid;
    int mc = (int)min(cnt[b], (unsigned)CAND_MAX);
    unsigned long long my = (i < mc) ? cand[(size_t)b * CAND_MAX + i] : 0ull;
    int rank = 0;
    int nt = (mc + 255) >> 8;
    for (int t = 0; t < nt; ++t) {
        int j = t * 256 + tid;
        sk[tid] = (j < mc) ? cand[(size_t)b * CAND_MAX + j] : 0ull;
        __syncthreads();
#pragma unroll 16
        for (int c = 0; c < 256; ++c) rank += (sk[c] > my) ? 1 : 0;
        __syncthreads();
    }
    if (i < mc && rank < PRE_NMS) {
        unsigned idx = ~(unsigned)(my & 0xFFFFFFFFull);
        sortedBoxes[(size_t)b * SORT_N + rank] = boxes[(size_t)b * N_PROP + idx];
    }
    if (i >= PRE_NMS && i < SORT_N) {
        sortedBoxes[(size_t)b * SORT_N + i] = make_float4(0.f, 0.f, 0.f, 0.f);
    }
}

// ---------------------------------------------------------------------------
// Kernel E: suppression bitmask, 64x64 tiles, upper triangle (cc >= rc).
// Lower-triangle words left unwritten (poison) -- never consulted: bits for
// j < i are only read before row i is OR'd into `removed`.
// ---------------------------------------------------------------------------
__global__ void iou_mask_kernel(const float4* __restrict__ sortedBoxes,
                                unsigned long long* __restrict__ mask) {
#pragma clang fp contract(off)
    int rc = blockIdx.x, cc = blockIdx.y, b = blockIdx.z;
    if (cc < rc) return;
    int t = threadIdx.x;
    __shared__ float4 colb[64];
    colb[t] = sortedBoxes[(size_t)b * SORT_N + cc * 64 + t];
    __syncthreads();
    int r = rc * 64 + t;
    float4 rb = sortedBoxes[(size_t)b * SORT_N + r];
    float rarea = (rb.z - rb.x) * (rb.w - rb.y);
    unsigned long long word = 0ull;
    for (int c = 0; c < 64; ++c) {
        int j = cc * 64 + c;
        float4 cb = colb[c];
        float carea = (cb.z - cb.x) * (cb.w - cb.y);
        float ltx = fmaxf(rb.x, cb.x);
        float lty = fmaxf(rb.y, cb.y);
        float rbx = fminf(rb.z, cb.z);
        float rby = fminf(rb.w, cb.w);
        float iw = fmaxf(rbx - ltx, 0.0f);
        float ih = fmaxf(rby - lty, 0.0f);
        float inter = iw * ih;
        float iou = inter / (rarea + carea - inter + 1e-9f);
        if (iou > NMS_TH && j > r) word |= (1ull << c);
    }
    mask[((size_t)b * SORT_N + r) * MASK_WORDS + cc] = word;
}

// ---------------------------------------------------------------------------
// Kernel F: serial greedy scan (one wave per image) + output write.
// Early-exits once 300 boxes are kept (rank >= 300 is dropped by reference).
// ---------------------------------------------------------------------------
__device__ inline unsigned long long bcast64(unsigned long long v, int src) {
    int lo = (int)(v & 0xFFFFFFFFull);
    int hi = (int)(v >> 32);
    lo = __shfl(lo, src);
    hi = __shfl(hi, src);
    return ((unsigned long long)(unsigned)hi << 32) | (unsigned)lo;
}

__global__ void nms_scan_kernel(const unsigned long long* __restrict__ mask,
                                const float4* __restrict__ sortedBoxes,
                                float* __restrict__ out) {
    int b = blockIdx.x;
    int lane = threadIdx.x;  // 0..63
    const unsigned long long* M = mask + (size_t)b * SORT_N * MASK_WORDS;
    __shared__ int kept_idx[POST_NMS];

    unsigned long long removed = 0ull;
    unsigned long long cur = 0ull;
    int kcnt = 0;
    unsigned long long m_next = M[lane];   // row 0, this lane's word
    unsigned long long mw_next = M[0];     // row 0, diagonal word

    for (int i = 0; i < PRE_NMS; ++i) {
        unsigned long long mrow = m_next;
        unsigned long long mw = mw_next;
        int inext = i + 1;  // row 4000 exists (SORT_N=4096), fully built
        m_next = M[(size_t)inext * MASK_WORDS + lane];
        mw_next = M[(size_t)inext * MASK_WORDS + (inext >> 6)];
        int w = i >> 6;
        int bit = i & 63;
        if (bit == 0) cur = bcast64(removed, w);
        bool kept = ((cur >> bit) & 1ull) == 0ull;
        if (kept) {
            removed |= mrow;
            cur |= mw;
            if (lane == 0) kept_idx[kcnt] = i;
            ++kcnt;
            if (kcnt >= POST_NMS) break;
        }
    }
    __syncthreads();
    for (int r = lane; r < POST_NMS; r += 64) {
        float* o = out + ((size_t)b * POST_NMS + r) * 5;
        float4 bx = make_float4(0.f, 0.f, 0.f, 0.f);
        if (r < kcnt) bx = sortedBoxes[(size_t)b * SORT_N + kept_idx[r]];
        o[0] = (float)b;
        o[1] = bx.x;
        o[2] = bx.y;
        o[3] = bx.z;
        o[4] = bx.w;
    }
}

// ---------------------------------------------------------------------------
extern "C" void kernel_launch(void* const* d_in, const int* in_sizes, int n_in,
                              void* d_out, int out_size, void* d_ws, size_t ws_size,
                              hipStream_t stream) {
    const float* scores  = (const float*)d_in[0];
    const float* deltas  = (const float*)d_in[1];
    const float* im_info = (const float*)d_in[2];
    const float* anchors = (const float*)d_in[3];
    float* out = (float*)d_out;

    char* ws = (char*)d_ws;
    size_t off = 0;
    float4* boxes = (float4*)(ws + off);
    off += (size_t)B_N * N_PROP * sizeof(float4);
    off = (off + 255) & ~(size_t)255;
    unsigned long long* keys = (unsigned long long*)(ws + off);
    off += (size_t)B_N * N_PROP * sizeof(unsigned long long);
    off = (off + 255) & ~(size_t)255;
    float4* sortedBoxes = (float4*)(ws + off);
    off += (size_t)B_N * SORT_N * sizeof(float4);
    off = (off + 255) & ~(size_t)255;
    unsigned long long* mask = (unsigned long long*)(ws + off);
    off += (size_t)B_N * SORT_N * MASK_WORDS * sizeof(unsigned long long);
    off = (off + 255) & ~(size_t)255;
    unsigned long long* cand = (unsigned long long*)(ws + off);
    off += (size_t)B_N * CAND_MAX * sizeof(unsigned long long);
    off = (off + 255) & ~(size_t)255;
    // zeroed region: ghist + cnt (contiguous)
    unsigned* ghist = (unsigned*)(ws + off);
    size_t zero_off = off;
    off += (size_t)B_N * NBINS * sizeof(unsigned);
    unsigned* cnt = (unsigned*)(ws + off);
    off += (size_t)B_N * sizeof(unsigned);
    size_t zero_bytes = off - zero_off;
    off = (off + 255) & ~(size_t)255;
    int* Tbuf = (int*)(ws + off);
    off += (size_t)B_N * sizeof(int);
    // total ~12.2 MB of ws

    hipMemsetAsync((void*)ghist, 0, zero_bytes, stream);

    int total = B_N * N_PROP;
    decode_kernel<<<(total + 255) / 256, 256, 0, stream>>>(
        scores, deltas, im_info, anchors, boxes, keys, ghist);
    findT_kernel<<<B_N, 64, 0, stream>>>(ghist, Tbuf);
    compact_kernel<<<dim3((N_PROP + 255) / 256, B_N), 256, 0, stream>>>(
        keys, Tbuf, cnt, cand);
    rank_scatter_kernel<<<dim3(CAND_MAX / 256, B_N), 256, 0, stream>>>(
        cand, cnt, boxes, sortedBoxes);
    iou_mask_kernel<<<dim3(64, 64, B_N), 64, 0, stream>>>(sortedBoxes, mask);
    nms_scan_kernel<<<B_N, 64, 0, stream>>>(mask, sortedBoxes, out);
}

// Round 3
// 309.632 us; speedup vs baseline: 1.1351x; 1.1351x over previous
//
#include <hip/hip_runtime.h>
#include <stdint.h>

#define A_N 9
#define H_N 50
#define W_N 76
#define HW_N (H_N * W_N)      // 3800
#define N_PROP (A_N * HW_N)   // 34200
#define B_N 4
#define PRE_NMS 4000
#define POST_NMS 300
#define NMS_TH 0.7f
#define SORT_N 4096
#define MASK_WORDS 64
#define CAND_MAX 5120
#define NBINS 4096

// ---------------------------------------------------------------------------
// Kernel A: decode + keys. Thread mapping is a-major (hw fastest) so every
// global load/store is coalesced. The key's low word encodes the REFERENCE
// index n_ref = hw*9 + a, so descending key order == jax.lax.top_k order
// (stable lower-index-first tie-break).
// ---------------------------------------------------------------------------
__global__ void decode_kernel(const float* __restrict__ scores,
                              const float* __restrict__ deltas,
                              const float* __restrict__ im_info,
                              const float* __restrict__ anchors,
                              float4* __restrict__ boxes,
                              unsigned long long* __restrict__ keys,
                              unsigned* __restrict__ ghist) {
#pragma clang fp contract(off)
    int gid = blockIdx.x * blockDim.x + threadIdx.x;
    if (gid >= B_N * N_PROP) return;
    int b = gid / N_PROP;
    int r = gid - b * N_PROP;
    int a = r / HW_N;          // fixed across a wave (3800 per a-slice)
    int hw = r - a * HW_N;     // consecutive across lanes
    int hy = hw / W_N;
    int wx = hw - hy * W_N;

    float sx = (float)wx * 16.0f;
    float sy = (float)hy * 16.0f;
    float ax1 = anchors[a * 4 + 0] + sx;
    float ay1 = anchors[a * 4 + 1] + sy;
    float ax2 = anchors[a * 4 + 2] + sx;
    float ay2 = anchors[a * 4 + 3] + sy;
    float aw = ax2 - ax1 + 1.0f;
    float ah = ay2 - ay1 + 1.0f;
    float cx = ax1 + 0.5f * aw;
    float cy = ay1 + 0.5f * ah;

    const float* db = deltas + ((size_t)b * 36 + (size_t)a * 4) * HW_N + hw;
    float d0 = db[0];
    float d1 = db[HW_N];
    float d2 = db[2 * HW_N];
    float d3 = db[3 * HW_N];

    float pcx = d0 * aw + cx;
    float pcy = d1 * ah + cy;
    float pw  = expf(d2) * aw;
    float ph  = expf(d3) * ah;

    float x1 = pcx - 0.5f * pw;
    float y1 = pcy - 0.5f * ph;
    float x2 = pcx + 0.5f * pw;
    float y2 = pcy + 0.5f * ph;

    float xhi = im_info[b * 3 + 1] - 1.0f;
    float yhi = im_info[b * 3 + 0] - 1.0f;
    x1 = fminf(fmaxf(x1, 0.0f), xhi);
    y1 = fminf(fmaxf(y1, 0.0f), yhi);
    x2 = fminf(fmaxf(x2, 0.0f), xhi);
    y2 = fminf(fmaxf(y2, 0.0f), yhi);

    boxes[gid] = make_float4(x1, y1, x2, y2);  // a-major layout

    float s = scores[((size_t)b * A_N + a) * HW_N + hw];
    unsigned f = __float_as_uint(s);
    unsigned sk = f ^ ((f & 0x80000000u) ? 0xFFFFFFFFu : 0x80000000u);
    unsigned n_ref = (unsigned)(hw * A_N + a);
    unsigned long long key = ((unsigned long long)sk << 32) | (unsigned)(~n_ref);
    keys[gid] = key;
    atomicAdd(&ghist[b * NBINS + (unsigned)(key >> 52)], 1u);
}

// ---------------------------------------------------------------------------
// Kernel B: per-image threshold bucket T.
// ---------------------------------------------------------------------------
__global__ void findT_kernel(const unsigned* __restrict__ ghist,
                             int* __restrict__ Tout) {
    __shared__ unsigned h[NBINS];
    __shared__ unsigned g[64];
    int b = blockIdx.x;
    int tid = threadIdx.x;  // 64 threads
    for (int i = tid; i < NBINS; i += 64) h[i] = ghist[b * NBINS + i];
    __syncthreads();
    unsigned s = 0;
    for (int j = 0; j < 64; ++j) s += h[tid * 64 + j];
    g[tid] = s;
    __syncthreads();
    if (tid == 0) {
        unsigned run = 0;
        int T = 0;
        for (int gi = 63; gi >= 0; --gi) {
            if (run + g[gi] >= PRE_NMS) {
                for (int j = 63; j >= 0; --j) {
                    run += h[gi * 64 + j];
                    if (run >= PRE_NMS) { T = gi * 64 + j; break; }
                }
                break;
            }
            run += g[gi];
        }
        Tout[b] = T;
    }
}

// ---------------------------------------------------------------------------
// Kernel C: compact candidates; wave-aggregated atomic (1 atomic / wave).
// ---------------------------------------------------------------------------
__global__ void compact_kernel(const unsigned long long* __restrict__ keys,
                               const int* __restrict__ T,
                               unsigned* __restrict__ cnt,
                               unsigned long long* __restrict__ cand) {
    int b = blockIdx.y;
    int n = blockIdx.x * 256 + threadIdx.x;
    bool pred = false;
    unsigned long long k = 0ull;
    if (n < N_PROP) {
        k = keys[(size_t)b * N_PROP + n];
        pred = ((int)(unsigned)(k >> 52) >= T[b]);
    }
    unsigned long long m = __ballot(pred);
    if (m) {
        int lane = threadIdx.x & 63;
        int lead = __ffsll((unsigned long long)m) - 1;
        unsigned base = 0;
        if (lane == lead) base = atomicAdd(&cnt[b], (unsigned)__popcll(m));
        base = __shfl((int)base, lead);
        if (pred) {
            unsigned pos = base + (unsigned)__popcll(m & ((1ull << lane) - 1ull));
            if (pos < CAND_MAX) cand[(size_t)b * CAND_MAX + pos] = k;
        }
    }
}

// ---------------------------------------------------------------------------
// Kernel D: exact rank by pairwise count; scatter boxes to sorted slots.
// Converts reference index -> a-major storage index for the gather.
// ---------------------------------------------------------------------------
__global__ __launch_bounds__(256) void rank_scatter_kernel(
    const unsigned long long* __restrict__ cand,
    const unsigned* __restrict__ cnt,
    const float4* __restrict__ boxes,
    float4* __restrict__ sortedBoxes) {
    __shared__ unsigned long long sk[256];
    int b = blockIdx.y;
    int tid = threadIdx.x;
    int i = blockIdx.x * 256 + tid;
    int mc = (int)min(cnt[b], (unsigned)CAND_MAX);
    unsigned long long my = (i < mc) ? cand[(size_t)b * CAND_MAX + i] : 0ull;
    int rank = 0;
    int nt = (mc + 255) >> 8;
    for (int t = 0; t < nt; ++t) {
        int j = t * 256 + tid;
        sk[tid] = (j < mc) ? cand[(size_t)b * CAND_MAX + j] : 0ull;
        __syncthreads();
#pragma unroll 16
        for (int c = 0; c < 256; ++c) rank += (sk[c] > my) ? 1 : 0;
        __syncthreads();
    }
    if (i < mc && rank < PRE_NMS) {
        unsigned n_ref = ~(unsigned)(my & 0xFFFFFFFFull);
        unsigned a = n_ref % A_N;
        unsigned hw = n_ref / A_N;
        sortedBoxes[(size_t)b * SORT_N + rank] =
            boxes[(size_t)b * N_PROP + a * HW_N + hw];
    }
    if (i >= PRE_NMS && i < SORT_N) {
        sortedBoxes[(size_t)b * SORT_N + i] = make_float4(0.f, 0.f, 0.f, 0.f);
    }
}

// ---------------------------------------------------------------------------
// Kernel E: suppression bitmask, 64x64 tiles, upper triangle (cc >= rc).
// ---------------------------------------------------------------------------
__global__ void iou_mask_kernel(const float4* __restrict__ sortedBoxes,
                                unsigned long long* __restrict__ mask) {
#pragma clang fp contract(off)
    int rc = blockIdx.x, cc = blockIdx.y, b = blockIdx.z;
    if (cc < rc) return;
    int t = threadIdx.x;
    __shared__ float4 colb[64];
    colb[t] = sortedBoxes[(size_t)b * SORT_N + cc * 64 + t];
    __syncthreads();
    int r = rc * 64 + t;
    float4 rb = sortedBoxes[(size_t)b * SORT_N + r];
    float rarea = (rb.z - rb.x) * (rb.w - rb.y);
    unsigned long long word = 0ull;
    for (int c = 0; c < 64; ++c) {
        int j = cc * 64 + c;
        float4 cb = colb[c];
        float carea = (cb.z - cb.x) * (cb.w - cb.y);
        float ltx = fmaxf(rb.x, cb.x);
        float lty = fmaxf(rb.y, cb.y);
        float rbx = fminf(rb.z, cb.z);
        float rby = fminf(rb.w, cb.w);
        float iw = fmaxf(rbx - ltx, 0.0f);
        float ih = fmaxf(rby - lty, 0.0f);
        float inter = iw * ih;
        float iou = inter / (rarea + carea - inter + 1e-9f);
        if (iou > NMS_TH && j > r) word |= (1ull << c);
    }
    mask[((size_t)b * SORT_N + r) * MASK_WORDS + cc] = word;
}

// ---------------------------------------------------------------------------
// Kernel F: group-tile greedy scan. One wave per image.
// Within a 64-box group only the diagonal mask word per box is needed;
// full mask rows are fetched ONLY for kept boxes (~400 instead of 4000).
// Pad boxes (4000..4095) are all-zero -> IoU 0 -> "kept" with zero box,
// which matches the reference's zero padding exactly.
// ---------------------------------------------------------------------------
__device__ inline unsigned long long bcast64(unsigned long long v, int src) {
    int lo = __shfl((int)(unsigned)(v & 0xFFFFFFFFull), src);
    int hi = __shfl((int)(unsigned)(v >> 32), src);
    return ((unsigned long long)(unsigned)hi << 32) | (unsigned)lo;
}

__global__ __launch_bounds__(64) void nms_scan_kernel(
    const unsigned long long* __restrict__ mask,
    const float4* __restrict__ sortedBoxes,
    float* __restrict__ out) {
    int b = blockIdx.x;
    int lane = threadIdx.x;  // 0..63
    const unsigned long long* M = mask + (size_t)b * SORT_N * MASK_WORDS;
    __shared__ int kept[POST_NMS];

    unsigned long long rem = 0ull;  // lane w: removed bits, boxes [w*64, w*64+64)
    int kcnt = 0;
    bool done = false;
    // prefetch diagonal word for group 0: lane i -> M[i][0]
    unsigned long long diag = M[(size_t)lane * MASK_WORDS + 0];

    for (int g = 0; g < 64; ++g) {
        unsigned long long D = diag;  // lane i: M[g*64+i][g]
        if (g < 63)
            diag = M[((size_t)(g + 1) * 64 + lane) * MASK_WORDS + (g + 1)];
        unsigned long long cur = bcast64(rem, g);
        unsigned long long pending = ~cur;     // not-yet-suppressed, in order
        unsigned long long alive_mask = 0ull;
        while (pending) {
            int bit = __builtin_ctzll(pending);  // next alive box
            if (lane == 0) kept[kcnt] = (g << 6) + bit;
            ++kcnt;
            alive_mask |= 1ull << bit;
            if (kcnt == POST_NMS) { done = true; break; }
            unsigned long long d = bcast64(D, bit);  // its in-group suppression
            pending &= ~(d | (1ull << bit));
        }
        if (done) break;
        // OR kept rows' full masks into distributed `rem` (8-wide batches;
        // duplicates of i0 pad the batch -- harmless re-OR).
        unsigned long long am = alive_mask;
        while (am) {
            int i0 = __builtin_ctzll(am); am &= am - 1;
            int i1 = am ? __builtin_ctzll(am) : i0; am = am ? (am & (am - 1)) : 0ull;
            int i2 = am ? __builtin_ctzll(am) : i0; am = am ? (am & (am - 1)) : 0ull;
            int i3 = am ? __builtin_ctzll(am) : i0; am = am ? (am & (am - 1)) : 0ull;
            int i4 = am ? __builtin_ctzll(am) : i0; am = am ? (am & (am - 1)) : 0ull;
            int i5 = am ? __builtin_ctzll(am) : i0; am = am ? (am & (am - 1)) : 0ull;
            int i6 = am ? __builtin_ctzll(am) : i0; am = am ? (am & (am - 1)) : 0ull;
            int i7 = am ? __builtin_ctzll(am) : i0; am = am ? (am & (am - 1)) : 0ull;
            size_t base = (size_t)g << 6;
            unsigned long long v0 = M[(base + i0) * MASK_WORDS + lane];
            unsigned long long v1 = M[(base + i1) * MASK_WORDS + lane];
            unsigned long long v2 = M[(base + i2) * MASK_WORDS + lane];
            unsigned long long v3 = M[(base + i3) * MASK_WORDS + lane];
            unsigned long long v4 = M[(base + i4) * MASK_WORDS + lane];
            unsigned long long v5 = M[(base + i5) * MASK_WORDS + lane];
            unsigned long long v6 = M[(base + i6) * MASK_WORDS + lane];
            unsigned long long v7 = M[(base + i7) * MASK_WORDS + lane];
            rem |= (v0 | v1) | (v2 | v3) | ((v4 | v5) | (v6 | v7));
        }
    }
    __syncthreads();
    for (int r = lane; r < POST_NMS; r += 64) {
        float* o = out + ((size_t)b * POST_NMS + r) * 5;
        float4 bx = make_float4(0.f, 0.f, 0.f, 0.f);
        if (r < kcnt) bx = sortedBoxes[(size_t)b * SORT_N + kept[r]];
        o[0] = (float)b;
        o[1] = bx.x;
        o[2] = bx.y;
        o[3] = bx.z;
        o[4] = bx.w;
    }
}

// ---------------------------------------------------------------------------
extern "C" void kernel_launch(void* const* d_in, const int* in_sizes, int n_in,
                              void* d_out, int out_size, void* d_ws, size_t ws_size,
                              hipStream_t stream) {
    const float* scores  = (const float*)d_in[0];
    const float* deltas  = (const float*)d_in[1];
    const float* im_info = (const float*)d_in[2];
    const float* anchors = (const float*)d_in[3];
    float* out = (float*)d_out;

    char* ws = (char*)d_ws;
    size_t off = 0;
    float4* boxes = (float4*)(ws + off);
    off += (size_t)B_N * N_PROP * sizeof(float4);
    off = (off + 255) & ~(size_t)255;
    unsigned long long* keys = (unsigned long long*)(ws + off);
    off += (size_t)B_N * N_PROP * sizeof(unsigned long long);
    off = (off + 255) & ~(size_t)255;
    float4* sortedBoxes = (float4*)(ws + off);
    off += (size_t)B_N * SORT_N * sizeof(float4);
    off = (off + 255) & ~(size_t)255;
    unsigned long long* mask = (unsigned long long*)(ws + off);
    off += (size_t)B_N * SORT_N * MASK_WORDS * sizeof(unsigned long long);
    off = (off + 255) & ~(size_t)255;
    unsigned long long* cand = (unsigned long long*)(ws + off);
    off += (size_t)B_N * CAND_MAX * sizeof(unsigned long long);
    off = (off + 255) & ~(size_t)255;
    // zeroed region: ghist + cnt (contiguous)
    unsigned* ghist = (unsigned*)(ws + off);
    size_t zero_off = off;
    off += (size_t)B_N * NBINS * sizeof(unsigned);
    unsigned* cnt = (unsigned*)(ws + off);
    off += (size_t)B_N * sizeof(unsigned);
    size_t zero_bytes = off - zero_off;
    off = (off + 255) & ~(size_t)255;
    int* Tbuf = (int*)(ws + off);
    off += (size_t)B_N * sizeof(int);

    hipMemsetAsync((void*)ghist, 0, zero_bytes, stream);

    int total = B_N * N_PROP;
    decode_kernel<<<(total + 255) / 256, 256, 0, stream>>>(
        scores, deltas, im_info, anchors, boxes, keys, ghist);
    findT_kernel<<<B_N, 64, 0, stream>>>(ghist, Tbuf);
    compact_kernel<<<dim3((N_PROP + 255) / 256, B_N), 256, 0, stream>>>(
        keys, Tbuf, cnt, cand);
    rank_scatter_kernel<<<dim3(CAND_MAX / 256, B_N), 256, 0, stream>>>(
        cand, cnt, boxes, sortedBoxes);
    iou_mask_kernel<<<dim3(64, 64, B_N), 64, 0, stream>>>(sortedBoxes, mask);
    nms_scan_kernel<<<B_N, 64, 0, stream>>>(mask, sortedBoxes, out);
}

// Round 4
// 289.586 us; speedup vs baseline: 1.2136x; 1.0692x over previous
//
#include <hip/hip_runtime.h>
#include <stdint.h>

#define A_N 9
#define H_N 50
#define W_N 76
#define HW_N (H_N * W_N)      // 3800
#define N_PROP (A_N * HW_N)   // 34200
#define B_N 4
#define PRE_NMS 4000
#define POST_NMS 300
#define NMS_TH 0.7f
#define SORT_N 4096
#define MASK_WORDS 64
#define CAND_MAX 5120
#define NBINS 4096

// ---------------------------------------------------------------------------
// Kernel A: decode + keys (a-major mapping -> all loads/stores coalesced).
// Key low word encodes REFERENCE index n_ref = hw*9 + a so descending key
// order == jax.lax.top_k order (stable lower-index-first tie-break).
// ---------------------------------------------------------------------------
__global__ void decode_kernel(const float* __restrict__ scores,
                              const float* __restrict__ deltas,
                              const float* __restrict__ im_info,
                              const float* __restrict__ anchors,
                              float4* __restrict__ boxes,
                              unsigned long long* __restrict__ keys,
                              unsigned* __restrict__ ghist) {
#pragma clang fp contract(off)
    int gid = blockIdx.x * blockDim.x + threadIdx.x;
    if (gid >= B_N * N_PROP) return;
    int b = gid / N_PROP;
    int r = gid - b * N_PROP;
    int a = r / HW_N;          // fixed across a wave
    int hw = r - a * HW_N;     // consecutive across lanes
    int hy = hw / W_N;
    int wx = hw - hy * W_N;

    float sx = (float)wx * 16.0f;
    float sy = (float)hy * 16.0f;
    float ax1 = anchors[a * 4 + 0] + sx;
    float ay1 = anchors[a * 4 + 1] + sy;
    float ax2 = anchors[a * 4 + 2] + sx;
    float ay2 = anchors[a * 4 + 3] + sy;
    float aw = ax2 - ax1 + 1.0f;
    float ah = ay2 - ay1 + 1.0f;
    float cx = ax1 + 0.5f * aw;
    float cy = ay1 + 0.5f * ah;

    const float* db = deltas + ((size_t)b * 36 + (size_t)a * 4) * HW_N + hw;
    float d0 = db[0];
    float d1 = db[HW_N];
    float d2 = db[2 * HW_N];
    float d3 = db[3 * HW_N];

    float pcx = d0 * aw + cx;
    float pcy = d1 * ah + cy;
    float pw  = expf(d2) * aw;
    float ph  = expf(d3) * ah;

    float x1 = pcx - 0.5f * pw;
    float y1 = pcy - 0.5f * ph;
    float x2 = pcx + 0.5f * pw;
    float y2 = pcy + 0.5f * ph;

    float xhi = im_info[b * 3 + 1] - 1.0f;
    float yhi = im_info[b * 3 + 0] - 1.0f;
    x1 = fminf(fmaxf(x1, 0.0f), xhi);
    y1 = fminf(fmaxf(y1, 0.0f), yhi);
    x2 = fminf(fmaxf(x2, 0.0f), xhi);
    y2 = fminf(fmaxf(y2, 0.0f), yhi);

    boxes[gid] = make_float4(x1, y1, x2, y2);  // a-major layout

    float s = scores[((size_t)b * A_N + a) * HW_N + hw];
    unsigned f = __float_as_uint(s);
    unsigned sk = f ^ ((f & 0x80000000u) ? 0xFFFFFFFFu : 0x80000000u);
    unsigned n_ref = (unsigned)(hw * A_N + a);
    unsigned long long key = ((unsigned long long)sk << 32) | (unsigned)(~n_ref);
    keys[gid] = key;
    atomicAdd(&ghist[b * NBINS + (unsigned)(key >> 52)], 1u);
}

// ---------------------------------------------------------------------------
// Kernel B: threshold bucket T via two wave-level suffix scans (no serial
// tid==0 loop). T = largest bin with suffix-count >= PRE_NMS.
// ---------------------------------------------------------------------------
__global__ __launch_bounds__(64) void findT_kernel(const unsigned* __restrict__ ghist,
                                                   int* __restrict__ Tout) {
    __shared__ unsigned h[NBINS];
    int b = blockIdx.x;
    int lane = threadIdx.x;  // 64
    for (int i = lane; i < NBINS; i += 64) h[i] = ghist[b * NBINS + i];
    __syncthreads();
    unsigned gsum = 0;
    for (int j = 0; j < 64; ++j) gsum += h[lane * 64 + j];
    unsigned s = gsum;
    for (int d = 1; d < 64; d <<= 1) {
        unsigned t = (unsigned)__shfl_down((int)s, d);
        if (lane + d < 64) s += t;
    }
    // s[lane] = suffix sum of coarse groups
    unsigned long long bal = __ballot(s >= PRE_NMS);
    int gstar = 63 - __builtin_clzll(bal);
    unsigned after = (gstar < 63) ? (unsigned)__builtin_amdgcn_readlane((int)s, gstar + 1) : 0u;
    unsigned R = PRE_NMS - after;
    unsigned s2 = h[gstar * 64 + lane];
    for (int d = 1; d < 64; d <<= 1) {
        unsigned t = (unsigned)__shfl_down((int)s2, d);
        if (lane + d < 64) s2 += t;
    }
    unsigned long long bal2 = __ballot(s2 >= R);
    int j = 63 - __builtin_clzll(bal2);
    if (lane == 0) Tout[b] = gstar * 64 + j;
}

// ---------------------------------------------------------------------------
// Kernel C: compact candidates; wave-aggregated atomic.
// ---------------------------------------------------------------------------
__global__ void compact_kernel(const unsigned long long* __restrict__ keys,
                               const int* __restrict__ T,
                               unsigned* __restrict__ cnt,
                               unsigned long long* __restrict__ cand) {
    int b = blockIdx.y;
    int n = blockIdx.x * 256 + threadIdx.x;
    bool pred = false;
    unsigned long long k = 0ull;
    if (n < N_PROP) {
        k = keys[(size_t)b * N_PROP + n];
        pred = ((int)(unsigned)(k >> 52) >= T[b]);
    }
    unsigned long long m = __ballot(pred);
    if (m) {
        int lane = threadIdx.x & 63;
        int lead = __ffsll((unsigned long long)m) - 1;
        unsigned base = 0;
        if (lane == lead) base = atomicAdd(&cnt[b], (unsigned)__popcll(m));
        base = __shfl((int)base, lead);
        if (pred) {
            unsigned pos = base + (unsigned)__popcll(m & ((1ull << lane) - 1ull));
            if (pos < CAND_MAX) cand[(size_t)b * CAND_MAX + pos] = k;
        }
    }
}

// ---------------------------------------------------------------------------
// Kernel D: exact rank by pairwise count, 4-way j-split per candidate
// (tid>>2 = candidate, tid&3 = quarter of j-space), shfl-reduce partials.
// ---------------------------------------------------------------------------
__global__ __launch_bounds__(256) void rank_scatter_kernel(
    const unsigned long long* __restrict__ cand,
    const unsigned* __restrict__ cnt,
    const float4* __restrict__ boxes,
    float4* __restrict__ sortedBoxes) {
    __shared__ unsigned long long sk[256];
    int b = blockIdx.y;
    int tid = threadIdx.x;
    int ci = blockIdx.x * 64 + (tid >> 2);
    int q = tid & 3;
    int mc = (int)min(cnt[b], (unsigned)CAND_MAX);
    unsigned long long my = (ci < mc) ? cand[(size_t)b * CAND_MAX + ci] : 0ull;
    int rank = 0;
    int nt = (mc + 255) >> 8;
    for (int t = 0; t < nt; ++t) {
        int j = t * 256 + tid;
        sk[tid] = (j < mc) ? cand[(size_t)b * CAND_MAX + j] : 0ull;
        __syncthreads();
#pragma unroll 16
        for (int c = 0; c < 64; ++c) {
            int cc = q * 64 + ((c + q * 17) & 63);  // stagger: avoid 4-way bank conflict
            rank += (sk[cc] > my) ? 1 : 0;
        }
        __syncthreads();
    }
    rank += __shfl_xor(rank, 1);
    rank += __shfl_xor(rank, 2);
    if (q == 0 && ci < mc && rank < PRE_NMS) {
        unsigned n_ref = ~(unsigned)(my & 0xFFFFFFFFull);
        unsigned a = n_ref % A_N;
        unsigned hw = n_ref / A_N;
        sortedBoxes[(size_t)b * SORT_N + rank] =
            boxes[(size_t)b * N_PROP + a * HW_N + hw];
    }
    if (q == 1) {
        int pi = blockIdx.x * 64 + (tid >> 2);
        if (pi >= PRE_NMS && pi < SORT_N)
            sortedBoxes[(size_t)b * SORT_N + pi] = make_float4(0.f, 0.f, 0.f, 0.f);
    }
}

// ---------------------------------------------------------------------------
// Kernel E: suppression bitmask -> COLUMN-MAJOR layout C[w*SORT_N + r].
// Store is coalesced (lane = row). Upper triangle only; lower-tri words stay
// poisoned but are provably consumed only after their read point has passed.
// ---------------------------------------------------------------------------
__global__ void iou_mask_kernel(const float4* __restrict__ sortedBoxes,
                                unsigned long long* __restrict__ colmaj) {
#pragma clang fp contract(off)
    int rc = blockIdx.x, cc = blockIdx.y, b = blockIdx.z;
    if (cc < rc) return;
    int t = threadIdx.x;
    __shared__ float4 colb[64];
    colb[t] = sortedBoxes[(size_t)b * SORT_N + cc * 64 + t];
    __syncthreads();
    int r = rc * 64 + t;
    float4 rb = sortedBoxes[(size_t)b * SORT_N + r];
    float rarea = (rb.z - rb.x) * (rb.w - rb.y);
    unsigned long long word = 0ull;
    for (int c = 0; c < 64; ++c) {
        int j = cc * 64 + c;
        float4 cb = colb[c];
        float carea = (cb.z - cb.x) * (cb.w - cb.y);
        float ltx = fmaxf(rb.x, cb.x);
        float lty = fmaxf(rb.y, cb.y);
        float rbx = fminf(rb.z, cb.z);
        float rby = fminf(rb.w, cb.w);
        float iw = fmaxf(rbx - ltx, 0.0f);
        float ih = fmaxf(rby - lty, 0.0f);
        float inter = iw * ih;
        float iou = inter / (rarea + carea - inter + 1e-9f);
        if (iou > NMS_TH && j > r) word |= (1ull << c);
    }
    colmaj[((size_t)b * MASK_WORDS + cc) * SORT_N + r] = word;  // coalesced
}

// ---------------------------------------------------------------------------
// Kernel F: group-tile greedy scan, latency-hidden.
//  - all broadcasts via v_readlane (VALU) instead of ds_bpermute
//  - per group g, words g+1..g+3 over group-g rows are prefetched one group
//    ahead (coalesced colmaj loads); contributions of g's kept boxes to the
//    next 3 groups' `cur` are computed in-register (carries d1c/e2c/e3c)
//  - full kept-row loads are parked in 3 register generations and OR'd into
//    `rem` only 3 groups later -> vmcnt wait has ~2.5 group-times of slack
// ---------------------------------------------------------------------------
__device__ inline unsigned long long rl64(unsigned long long v, int src) {
    unsigned lo = (unsigned)__builtin_amdgcn_readlane((int)(unsigned)(v & 0xFFFFFFFFull), src);
    unsigned hi = (unsigned)__builtin_amdgcn_readlane((int)(unsigned)(v >> 32), src);
    return ((unsigned long long)hi << 32) | lo;
}

__global__ __launch_bounds__(64) void nms_scan_kernel(
    const unsigned long long* __restrict__ colmaj,
    const float4* __restrict__ sortedBoxes,
    float* __restrict__ out) {
    int b = blockIdx.x;
    int lane = threadIdx.x;  // 0..63
    const unsigned long long* C = colmaj + (size_t)b * MASK_WORDS * SORT_N;
    __shared__ int kept[POST_NMS];

    unsigned long long rem = 0ull;          // lane w: removed bits of group w
    unsigned long long gA[16], gB[16], gC[16];
#pragma unroll
    for (int k = 0; k < 16; ++k) { gA[k] = 0; gB[k] = 0; gC[k] = 0; }

    // prefetch group 0: diag + words 1..3 over rows 0..63
    unsigned long long diag = C[lane];
    unsigned long long col1 = C[(size_t)1 * SORT_N + lane];
    unsigned long long col2 = C[(size_t)2 * SORT_N + lane];
    unsigned long long col3 = C[(size_t)3 * SORT_N + lane];

    unsigned long long d1c = 0, e2c = 0, e3c = 0;
    unsigned long long u2a = 0, u3a = 0, u3b = 0;
    int kcnt = 0;
    bool done = false;

    for (int g = 0; g < 64; ++g) {
        unsigned long long Dg = diag, c1 = col1, c2 = col2, c3 = col3;
        // issue prefetches for group g+1
        if (g < 63) {
            size_t rbase = (size_t)(g + 1) << 6;
            diag = C[(size_t)(g + 1) * SORT_N + rbase + lane];
            col1 = (g + 2 < 64) ? C[(size_t)(g + 2) * SORT_N + rbase + lane] : 0ull;
            col2 = (g + 3 < 64) ? C[(size_t)(g + 3) * SORT_N + rbase + lane] : 0ull;
            col3 = (g + 4 < 64) ? C[(size_t)(g + 4) * SORT_N + rbase + lane] : 0ull;
        }
        // retire generation A (rows from group g-3)
        unsigned long long accA = ((gA[0] | gA[1]) | (gA[2] | gA[3])) |
                                  ((gA[4] | gA[5]) | (gA[6] | gA[7])) |
                                  ((gA[8] | gA[9]) | (gA[10] | gA[11])) |
                                  ((gA[12] | gA[13]) | (gA[14] | gA[15]));
        rem |= accA;
#pragma unroll
        for (int k = 0; k < 16; ++k) { gA[k] = gB[k]; gB[k] = gC[k]; gC[k] = 0; }

        unsigned long long cur = rl64(rem, g) | d1c | e2c | e3c;
        unsigned long long pending = ~cur;
        unsigned long long alive = 0ull;
        while (pending) {
            int bit = __builtin_ctzll(pending);
            if (lane == 0) kept[kcnt] = (g << 6) + bit;
            ++kcnt;
            alive |= 1ull << bit;
            if (kcnt == POST_NMS) { done = true; break; }
            unsigned long long d = rl64(Dg, bit);
            pending &= ~(d | (1ull << bit));
        }
        if (done) break;

        // fast-path contributions of g's kept boxes to words g+1..g+3
        unsigned long long s1 = 0, s2 = 0, s3 = 0;
        unsigned long long am = alive;
        while (am) {
            int i = __builtin_ctzll(am); am &= am - 1;
            s1 |= rl64(c1, i);
            s2 |= rl64(c2, i);
            s3 |= rl64(c3, i);
        }
        e3c = u3b; u3b = u3a; u3a = s3;
        e2c = u2a; u2a = s2;
        d1c = s1;

        // full row loads for kept rows (deferred OR, 16-wide batch)
        unsigned long long am2 = alive;
        if (am2) {
            int idx[16];
            int i0 = __builtin_ctzll(am2); am2 &= am2 - 1;
            idx[0] = i0;
#pragma unroll
            for (int k = 1; k < 16; ++k) {
                idx[k] = am2 ? __builtin_ctzll(am2) : i0;
                am2 = am2 ? (am2 & (am2 - 1)) : 0ull;
            }
            size_t base = (size_t)lane * SORT_N + ((size_t)g << 6);
#pragma unroll
            for (int k = 0; k < 16; ++k) gC[k] = C[base + idx[k]];
            while (am2) {  // >16 kept in one group: rare, accept the stall
                int j = __builtin_ctzll(am2); am2 &= am2 - 1;
                gC[0] |= C[base + j];
            }
        }
    }
    __syncthreads();
    for (int r = lane; r < POST_NMS; r += 64) {
        float* o = out + ((size_t)b * POST_NMS + r) * 5;
        float4 bx = make_float4(0.f, 0.f, 0.f, 0.f);
        if (r < kcnt) bx = sortedBoxes[(size_t)b * SORT_N + kept[r]];
        o[0] = (float)b;
        o[1] = bx.x;
        o[2] = bx.y;
        o[3] = bx.z;
        o[4] = bx.w;
    }
}

// ---------------------------------------------------------------------------
extern "C" void kernel_launch(void* const* d_in, const int* in_sizes, int n_in,
                              void* d_out, int out_size, void* d_ws, size_t ws_size,
                              hipStream_t stream) {
    const float* scores  = (const float*)d_in[0];
    const float* deltas  = (const float*)d_in[1];
    const float* im_info = (const float*)d_in[2];
    const float* anchors = (const float*)d_in[3];
    float* out = (float*)d_out;

    char* ws = (char*)d_ws;
    size_t off = 0;
    float4* boxes = (float4*)(ws + off);
    off += (size_t)B_N * N_PROP * sizeof(float4);
    off = (off + 255) & ~(size_t)255;
    unsigned long long* keys = (unsigned long long*)(ws + off);
    off += (size_t)B_N * N_PROP * sizeof(unsigned long long);
    off = (off + 255) & ~(size_t)255;
    float4* sortedBoxes = (float4*)(ws + off);
    off += (size_t)B_N * SORT_N * sizeof(float4);
    off = (off + 255) & ~(size_t)255;
    unsigned long long* colmaj = (unsigned long long*)(ws + off);
    off += (size_t)B_N * MASK_WORDS * SORT_N * sizeof(unsigned long long);
    off = (off + 255) & ~(size_t)255;
    unsigned long long* cand = (unsigned long long*)(ws + off);
    off += (size_t)B_N * CAND_MAX * sizeof(unsigned long long);
    off = (off + 255) & ~(size_t)255;
    unsigned* ghist = (unsigned*)(ws + off);
    size_t zero_off = off;
    off += (size_t)B_N * NBINS * sizeof(unsigned);
    unsigned* cnt = (unsigned*)(ws + off);
    off += (size_t)B_N * sizeof(unsigned);
    size_t zero_bytes = off - zero_off;
    off = (off + 255) & ~(size_t)255;
    int* Tbuf = (int*)(ws + off);
    off += (size_t)B_N * sizeof(int);

    hipMemsetAsync((void*)ghist, 0, zero_bytes, stream);

    int total = B_N * N_PROP;
    decode_kernel<<<(total + 255) / 256, 256, 0, stream>>>(
        scores, deltas, im_info, anchors, boxes, keys, ghist);
    findT_kernel<<<B_N, 64, 0, stream>>>(ghist, Tbuf);
    compact_kernel<<<dim3((N_PROP + 255) / 256, B_N), 256, 0, stream>>>(
        keys, Tbuf, cnt, cand);
    rank_scatter_kernel<<<dim3(CAND_MAX / 64, B_N), 256, 0, stream>>>(
        cand, cnt, boxes, sortedBoxes);
    iou_mask_kernel<<<dim3(64, 64, B_N), 64, 0, stream>>>(sortedBoxes, colmaj);
    nms_scan_kernel<<<B_N, 64, 0, stream>>>(colmaj, sortedBoxes, out);
}